// Round 1
// baseline (3195.791 us; speedup 1.0000x reference)
//
#include <hip/hip_runtime.h>
#include <hip/hip_bf16.h>

#define D 128
#define LN_EPS 1e-12f

// ---------------------------------------------------------------------------
// Kernel 1: fused 4-table embedding gather + LayerNorm.  One wave per node,
// each lane owns 2 consecutive features (float2).
// ---------------------------------------------------------------------------
__global__ __launch_bounds__(256) void embed_ln_kernel(
    const int* __restrict__ x,
    const float* __restrict__ syn, const float* __restrict__ lem,
    const float* __restrict__ pos, const float* __restrict__ sen,
    const float* __restrict__ g, const float* __restrict__ b,
    float* __restrict__ h0, int n) {
  int node = blockIdx.x * 4 + (threadIdx.x >> 6);
  if (node >= n) return;
  int lane = threadIdx.x & 63;
  int4 xi = ((const int4*)x)[node];  // [syn, pos, sen, lem] column order 0..3
  float2 v0 = ((const float2*)(syn + (size_t)xi.x * D))[lane];
  float2 v1 = ((const float2*)(pos + (size_t)xi.y * D))[lane];
  float2 v2 = ((const float2*)(sen + (size_t)xi.z * D))[lane];
  float2 v3 = ((const float2*)(lem + (size_t)xi.w * D))[lane];
  float a = v0.x + v1.x + v2.x + v3.x;
  float c = v0.y + v1.y + v2.y + v3.y;
  float sum = a + c;
#pragma unroll
  for (int off = 32; off; off >>= 1) sum += __shfl_xor(sum, off);
  float mu = sum * (1.0f / 128.0f);
  float da = a - mu, dc = c - mu;
  float sq = da * da + dc * dc;
#pragma unroll
  for (int off = 32; off; off >>= 1) sq += __shfl_xor(sq, off);
  float rstd = rsqrtf(sq * (1.0f / 128.0f) + LN_EPS);
  float2 gg = ((const float2*)g)[lane];
  float2 bb = ((const float2*)b)[lane];
  float2 o;
  o.x = da * rstd * gg.x + bb.x;
  o.y = dc * rstd * gg.y + bb.y;
  ((float2*)(h0 + (size_t)node * D))[lane] = o;
}

// ---------------------------------------------------------------------------
// Kernel 2: edge scatter.  32 lanes per edge, each lane does a float4 gather
// of h[src] and 4 native fp32 atomic adds into agg[dst].
// ---------------------------------------------------------------------------
__global__ __launch_bounds__(256) void scatter_kernel(
    const int* __restrict__ src, const int* __restrict__ dst,
    const float* __restrict__ h, float* __restrict__ agg,
    float* __restrict__ cnt, int nEdges, int addCnt) {
  long long t = (long long)blockIdx.x * blockDim.x + threadIdx.x;
  int e = (int)(t >> 5);
  if (e >= nEdges) return;
  int l = (int)(t & 31);
  int s = src[e], d = dst[e];
  float4 v = ((const float4*)(h + (size_t)s * D))[l];
  float* ap = agg + (size_t)d * D + l * 4;
  unsafeAtomicAdd(ap + 0, v.x);
  unsafeAtomicAdd(ap + 1, v.y);
  unsafeAtomicAdd(ap + 2, v.z);
  unsafeAtomicAdd(ap + 3, v.w);
  if (addCnt && l == 0) unsafeAtomicAdd(cnt + d, 1.0f);
}

// ---------------------------------------------------------------------------
// Kernel 3: SAGE linear layer:
//   out[i][j] = bl[j] + sum_k (agg[i][k]/max(cnt[i],1))*Wl[j][k]
//                     + sum_k  hin[i][k]*Wr[j][k]        (+ optional ReLU)
// One wave handles 8 nodes; node features staged in LDS (broadcast reads),
// weight rows streamed from L2 once per 8 nodes.
// ---------------------------------------------------------------------------
#define NPW 8
__global__ __launch_bounds__(256) void sage_layer_kernel(
    const float* __restrict__ agg, const float* __restrict__ cnt,
    const float* __restrict__ hin,
    const float* __restrict__ Wl, const float* __restrict__ bl,
    const float* __restrict__ Wr,
    float* __restrict__ out, int n, int doRelu) {
  __shared__ float ldsA[4][NPW][D];
  __shared__ float ldsH[4][NPW][D];
  int wave = threadIdx.x >> 6;
  int lane = threadIdx.x & 63;
  int base = (blockIdx.x * 4 + wave) * NPW;

#pragma unroll
  for (int nn = 0; nn < NPW; ++nn) {
    int node = base + nn;
    if (node >= n) node = n - 1;  // clamp (stores guarded below)
    float inv = 1.0f / fmaxf(cnt[node], 1.0f);
    float2 av = ((const float2*)(agg + (size_t)node * D))[lane];
    float2 hv = ((const float2*)(hin + (size_t)node * D))[lane];
    ldsA[wave][nn][lane * 2] = av.x * inv;
    ldsA[wave][nn][lane * 2 + 1] = av.y * inv;
    ldsH[wave][nn][lane * 2] = hv.x;
    ldsH[wave][nn][lane * 2 + 1] = hv.y;
  }
  __syncthreads();

#pragma unroll
  for (int jj = 0; jj < 2; ++jj) {
    int j = lane + jj * 64;
    const float4* wl4 = (const float4*)(Wl + (size_t)j * D);
    const float4* wr4 = (const float4*)(Wr + (size_t)j * D);
    float bias = bl[j];
    float acc[NPW];
#pragma unroll
    for (int nn = 0; nn < NPW; ++nn) acc[nn] = 0.0f;
    for (int k4 = 0; k4 < D / 4; ++k4) {
      float4 wlv = wl4[k4];
      float4 wrv = wr4[k4];
#pragma unroll
      for (int nn = 0; nn < NPW; ++nn) {
        float4 a = ((const float4*)ldsA[wave][nn])[k4];
        float4 h = ((const float4*)ldsH[wave][nn])[k4];
        acc[nn] += a.x * wlv.x + a.y * wlv.y + a.z * wlv.z + a.w * wlv.w +
                   h.x * wrv.x + h.y * wrv.y + h.z * wrv.z + h.w * wrv.w;
      }
    }
#pragma unroll
    for (int nn = 0; nn < NPW; ++nn) {
      int node = base + nn;
      if (node < n) {
        float v = acc[nn] + bias;
        out[(size_t)node * D + j] = doRelu ? fmaxf(v, 0.0f) : v;
      }
    }
  }
}

// ---------------------------------------------------------------------------
extern "C" void kernel_launch(void* const* d_in, const int* in_sizes, int n_in,
                              void* d_out, int out_size, void* d_ws,
                              size_t ws_size, hipStream_t stream) {
  const int* x = (const int*)d_in[0];
  const int* edge = (const int*)d_in[1];
  const float* syn = (const float*)d_in[2];
  const float* lem = (const float*)d_in[3];
  const float* pos = (const float*)d_in[4];
  const float* sen = (const float*)d_in[5];
  const float* ln_g = (const float*)d_in[6];
  const float* ln_b = (const float*)d_in[7];
  const float* Wl0 = (const float*)d_in[8];
  const float* bl0 = (const float*)d_in[9];
  const float* Wr0 = (const float*)d_in[10];
  const float* Wl1 = (const float*)d_in[11];
  const float* bl1 = (const float*)d_in[12];
  const float* Wr1 = (const float*)d_in[13];

  int n = in_sizes[0] / 4;
  int E = in_sizes[1] / 2;
  const int* srcI = edge;
  const int* dstI = edge + E;
  float* outp = (float*)d_out;

  size_t rowElems = (size_t)n * D;
  size_t need = (3 * rowElems + n) * sizeof(float);
  float* h0;
  float* hmid;
  float* agg;
  float* cnt;
  if (ws_size >= need) {
    h0 = (float*)d_ws;
    hmid = h0 + rowElems;
    agg = hmid + rowElems;
    cnt = agg + rowElems;
  } else {
    // tight-workspace fallback: stage layer-0 output in d_out (safe: layer-1
    // kernel reads each node row before its own block rewrites it)
    h0 = (float*)d_ws;
    agg = h0 + rowElems;
    cnt = agg + rowElems;
    hmid = outp;
  }

  int nodeBlocks = (n + 3) / 4;
  embed_ln_kernel<<<nodeBlocks, 256, 0, stream>>>(x, syn, lem, pos, sen, ln_g,
                                                  ln_b, h0, n);

  hipMemsetAsync(agg, 0, (rowElems + n) * sizeof(float), stream);

  long long tThreads = (long long)E * 32;
  int sBlocks = (int)((tThreads + 255) / 256);
  scatter_kernel<<<sBlocks, 256, 0, stream>>>(srcI, dstI, h0, agg, cnt, E, 1);

  int lBlocks = (n + 4 * NPW - 1) / (4 * NPW);
  sage_layer_kernel<<<lBlocks, 256, 0, stream>>>(agg, cnt, h0, Wl0, bl0, Wr0,
                                                 hmid, n, 1);

  hipMemsetAsync(agg, 0, rowElems * sizeof(float), stream);
  scatter_kernel<<<sBlocks, 256, 0, stream>>>(srcI, dstI, hmid, agg, cnt, E, 0);

  sage_layer_kernel<<<lBlocks, 256, 0, stream>>>(agg, cnt, hmid, Wl1, bl1, Wr1,
                                                 outp, n, 0);
}

// Round 2
// 726.873 us; speedup vs baseline: 4.3966x; 4.3966x over previous
//
#include <hip/hip_runtime.h>
#include <hip/hip_bf16.h>

#define D 128
#define LN_EPS 1e-12f

// ---------------------------------------------------------------------------
// Kernel 1: fused 4-table embedding gather + LayerNorm.  One wave per node,
// each lane owns 2 consecutive features (float2).
// ---------------------------------------------------------------------------
__global__ __launch_bounds__(256) void embed_ln_kernel(
    const int* __restrict__ x,
    const float* __restrict__ syn, const float* __restrict__ lem,
    const float* __restrict__ pos, const float* __restrict__ sen,
    const float* __restrict__ g, const float* __restrict__ b,
    float* __restrict__ h0, int n) {
  int node = blockIdx.x * 4 + (threadIdx.x >> 6);
  if (node >= n) return;
  int lane = threadIdx.x & 63;
  int4 xi = ((const int4*)x)[node];  // columns [syn, pos, sen, lem]
  float2 v0 = ((const float2*)(syn + (size_t)xi.x * D))[lane];
  float2 v1 = ((const float2*)(pos + (size_t)xi.y * D))[lane];
  float2 v2 = ((const float2*)(sen + (size_t)xi.z * D))[lane];
  float2 v3 = ((const float2*)(lem + (size_t)xi.w * D))[lane];
  float a = v0.x + v1.x + v2.x + v3.x;
  float c = v0.y + v1.y + v2.y + v3.y;
  float sum = a + c;
#pragma unroll
  for (int off = 32; off; off >>= 1) sum += __shfl_xor(sum, off);
  float mu = sum * (1.0f / 128.0f);
  float da = a - mu, dc = c - mu;
  float sq = da * da + dc * dc;
#pragma unroll
  for (int off = 32; off; off >>= 1) sq += __shfl_xor(sq, off);
  float rstd = rsqrtf(sq * (1.0f / 128.0f) + LN_EPS);
  float2 gg = ((const float2*)g)[lane];
  float2 bb = ((const float2*)b)[lane];
  float2 o;
  o.x = da * rstd * gg.x + bb.x;
  o.y = dc * rstd * gg.y + bb.y;
  ((float2*)(h0 + (size_t)node * D))[lane] = o;
}

// ---------------------------------------------------------------------------
// CSR build: histogram of dst, block-scan to row_ptr, bucket fill of src ids.
// 1.6M int atomics on 200 KB of counters (L2-resident) replaces 102M fp32
// atomics on a 25.6 MB array.
// ---------------------------------------------------------------------------
__global__ __launch_bounds__(256) void hist_kernel(const int* __restrict__ dst,
                                                   int* __restrict__ counts,
                                                   int nEdges) {
  int e = blockIdx.x * 256 + threadIdx.x;
  if (e < nEdges) atomicAdd(&counts[dst[e]], 1);
}

__global__ __launch_bounds__(1024) void scan_kernel(const int* __restrict__ counts,
                                                    int* __restrict__ row_ptr,
                                                    int n) {
  __shared__ int sums[1024];
  int t = threadIdx.x;
  int CH = (n + 1023) >> 10;
  int beg = t * CH;
  int end = min(beg + CH, n);
  int s = 0;
  for (int i = beg; i < end; ++i) s += counts[i];
  sums[t] = s;
  __syncthreads();
  for (int off = 1; off < 1024; off <<= 1) {
    int u = (t >= off) ? sums[t - off] : 0;
    __syncthreads();
    sums[t] += u;
    __syncthreads();
  }
  int run = sums[t] - s;  // exclusive prefix of this chunk
  for (int i = beg; i < end; ++i) {
    row_ptr[i] = run;
    run += counts[i];
  }
  if (t == 1023) row_ptr[n] = sums[1023];
}

__global__ __launch_bounds__(256) void fill_kernel(const int* __restrict__ src,
                                                   const int* __restrict__ dst,
                                                   const int* __restrict__ row_ptr,
                                                   int* __restrict__ cursor,
                                                   int* __restrict__ adj,
                                                   int nEdges) {
  int e = blockIdx.x * 256 + threadIdx.x;
  if (e >= nEdges) return;
  int d = dst[e];
  int p = atomicAdd(&cursor[d], 1);
  adj[row_ptr[d] + p] = src[e];
}

// ---------------------------------------------------------------------------
// Gather-based mean aggregation: one wave per node walks its in-neighbor
// list, accumulates float2/lane in registers, single write of the mean row.
// ---------------------------------------------------------------------------
__global__ __launch_bounds__(256) void gather_agg_kernel(
    const int* __restrict__ row_ptr, const int* __restrict__ adj,
    const float* __restrict__ h, float* __restrict__ agg, int n) {
  int node = blockIdx.x * 4 + (threadIdx.x >> 6);
  if (node >= n) return;
  int lane = threadIdx.x & 63;
  int beg = row_ptr[node], end = row_ptr[node + 1];
  float ax0 = 0.f, ay0 = 0.f, ax1 = 0.f, ay1 = 0.f;
  float ax2 = 0.f, ay2 = 0.f, ax3 = 0.f, ay3 = 0.f;
  int i = beg;
  for (; i + 4 <= end; i += 4) {
    int s0 = adj[i], s1 = adj[i + 1], s2 = adj[i + 2], s3 = adj[i + 3];
    float2 v0 = ((const float2*)(h + (size_t)s0 * D))[lane];
    float2 v1 = ((const float2*)(h + (size_t)s1 * D))[lane];
    float2 v2 = ((const float2*)(h + (size_t)s2 * D))[lane];
    float2 v3 = ((const float2*)(h + (size_t)s3 * D))[lane];
    ax0 += v0.x; ay0 += v0.y;
    ax1 += v1.x; ay1 += v1.y;
    ax2 += v2.x; ay2 += v2.y;
    ax3 += v3.x; ay3 += v3.y;
  }
  for (; i < end; ++i) {
    int s0 = adj[i];
    float2 v0 = ((const float2*)(h + (size_t)s0 * D))[lane];
    ax0 += v0.x; ay0 += v0.y;
  }
  float inv = 1.0f / fmaxf((float)(end - beg), 1.0f);
  float2 o;
  o.x = (ax0 + ax1 + ax2 + ax3) * inv;
  o.y = (ay0 + ay1 + ay2 + ay3) * inv;
  ((float2*)(agg + (size_t)node * D))[lane] = o;
}

// ---------------------------------------------------------------------------
// SAGE linear layer: out[i][j] = bl[j] + agg[i]·Wl[j] + hin[i]·Wr[j]
// (mean already folded into agg).  One wave handles 8 nodes staged in LDS;
// weight rows streamed from L2 once per 8 nodes.
// ---------------------------------------------------------------------------
#define NPW 8
__global__ __launch_bounds__(256) void sage_layer_kernel(
    const float* __restrict__ agg, const float* __restrict__ hin,
    const float* __restrict__ Wl, const float* __restrict__ bl,
    const float* __restrict__ Wr,
    float* __restrict__ out, int n, int doRelu) {
  __shared__ float ldsA[4][NPW][D];
  __shared__ float ldsH[4][NPW][D];
  int wave = threadIdx.x >> 6;
  int lane = threadIdx.x & 63;
  int base = (blockIdx.x * 4 + wave) * NPW;

#pragma unroll
  for (int nn = 0; nn < NPW; ++nn) {
    int node = base + nn;
    if (node >= n) node = n - 1;  // clamp (stores guarded below)
    float2 av = ((const float2*)(agg + (size_t)node * D))[lane];
    float2 hv = ((const float2*)(hin + (size_t)node * D))[lane];
    ldsA[wave][nn][lane * 2] = av.x;
    ldsA[wave][nn][lane * 2 + 1] = av.y;
    ldsH[wave][nn][lane * 2] = hv.x;
    ldsH[wave][nn][lane * 2 + 1] = hv.y;
  }
  __syncthreads();

#pragma unroll
  for (int jj = 0; jj < 2; ++jj) {
    int j = lane + jj * 64;
    const float4* wl4 = (const float4*)(Wl + (size_t)j * D);
    const float4* wr4 = (const float4*)(Wr + (size_t)j * D);
    float bias = bl[j];
    float acc[NPW];
#pragma unroll
    for (int nn = 0; nn < NPW; ++nn) acc[nn] = 0.0f;
    for (int k4 = 0; k4 < D / 4; ++k4) {
      float4 wlv = wl4[k4];
      float4 wrv = wr4[k4];
#pragma unroll
      for (int nn = 0; nn < NPW; ++nn) {
        float4 a = ((const float4*)ldsA[wave][nn])[k4];
        float4 h = ((const float4*)ldsH[wave][nn])[k4];
        acc[nn] += a.x * wlv.x + a.y * wlv.y + a.z * wlv.z + a.w * wlv.w +
                   h.x * wrv.x + h.y * wrv.y + h.z * wrv.z + h.w * wrv.w;
      }
    }
#pragma unroll
    for (int nn = 0; nn < NPW; ++nn) {
      int node = base + nn;
      if (node < n) {
        float v = acc[nn] + bias;
        out[(size_t)node * D + j] = doRelu ? fmaxf(v, 0.0f) : v;
      }
    }
  }
}

// ---------------------------------------------------------------------------
extern "C" void kernel_launch(void* const* d_in, const int* in_sizes, int n_in,
                              void* d_out, int out_size, void* d_ws,
                              size_t ws_size, hipStream_t stream) {
  const int* x = (const int*)d_in[0];
  const int* edge = (const int*)d_in[1];
  const float* syn = (const float*)d_in[2];
  const float* lem = (const float*)d_in[3];
  const float* pos = (const float*)d_in[4];
  const float* sen = (const float*)d_in[5];
  const float* ln_g = (const float*)d_in[6];
  const float* ln_b = (const float*)d_in[7];
  const float* Wl0 = (const float*)d_in[8];
  const float* bl0 = (const float*)d_in[9];
  const float* Wr0 = (const float*)d_in[10];
  const float* Wl1 = (const float*)d_in[11];
  const float* bl1 = (const float*)d_in[12];
  const float* Wr1 = (const float*)d_in[13];

  int n = in_sizes[0] / 4;
  int E = in_sizes[1] / 2;
  const int* srcI = edge;
  const int* dstI = edge + E;
  float* outp = (float*)d_out;

  size_t rowElems = (size_t)n * D;
  // Workspace layout (floats/ints are both 4 B):
  //   h0[rowElems] | hmid[rowElems] | agg[rowElems] |
  //   row_ptr[n+1] | counts[n] | cursor[n] | adj[E]
  size_t intElems = (size_t)(3 * n + 1) + (size_t)E;
  size_t needFull = (3 * rowElems + intElems) * sizeof(float);

  float* h0;
  float* hmid;
  float* agg;
  if (ws_size >= needFull) {
    h0 = (float*)d_ws;
    hmid = h0 + rowElems;
    agg = hmid + rowElems;
  } else {
    // tight-workspace fallback: stage layer-0 output in d_out (safe: the
    // layer-1 sage kernel stages each node row into LDS before overwriting)
    h0 = (float*)d_ws;
    agg = h0 + rowElems;
    hmid = outp;
  }
  int* row_ptr = (int*)(agg + rowElems);
  int* counts = row_ptr + (n + 1);
  int* cursor = counts + n;
  int* adj = cursor + n;

  // zero counts + cursor (contiguous)
  hipMemsetAsync(counts, 0, 2 * (size_t)n * sizeof(int), stream);

  int nodeBlocks = (n + 3) / 4;
  embed_ln_kernel<<<nodeBlocks, 256, 0, stream>>>(x, syn, lem, pos, sen, ln_g,
                                                  ln_b, h0, n);

  int eBlocks = (E + 255) / 256;
  hist_kernel<<<eBlocks, 256, 0, stream>>>(dstI, counts, E);
  scan_kernel<<<1, 1024, 0, stream>>>(counts, row_ptr, n);
  fill_kernel<<<eBlocks, 256, 0, stream>>>(srcI, dstI, row_ptr, cursor, adj, E);

  gather_agg_kernel<<<nodeBlocks, 256, 0, stream>>>(row_ptr, adj, h0, agg, n);

  int lBlocks = (n + 4 * NPW - 1) / (4 * NPW);
  sage_layer_kernel<<<lBlocks, 256, 0, stream>>>(agg, h0, Wl0, bl0, Wr0, hmid,
                                                 n, 1);

  gather_agg_kernel<<<nodeBlocks, 256, 0, stream>>>(row_ptr, adj, hmid, agg, n);

  sage_layer_kernel<<<lBlocks, 256, 0, stream>>>(agg, hmid, Wl1, bl1, Wr1, outp,
                                                 n, 0);
}